// Round 9
// baseline (112.791 us; speedup 1.0000x reference)
//
#include <hip/hip_runtime.h>
#include <stdint.h>

typedef unsigned int u32;
typedef unsigned short u16;
typedef unsigned long long u64;
typedef __bf16 bf16x8 __attribute__((ext_vector_type(8)));
typedef float f32x4 __attribute__((ext_vector_type(4)));
typedef u32 u32x4 __attribute__((ext_vector_type(4)));

#define IN_DIM 512

__device__ __forceinline__ u16 bfr(float f) {
  __bf16 h = (__bf16)f;
  return __builtin_bit_cast(u16, h);
}
__device__ __forceinline__ u16 f2bf(float f) {
  u32 u = __builtin_bit_cast(u32, f);
  u += 0x7fffu + ((u >> 16) & 1u);
  return (u16)(u >> 16);
}
__device__ __forceinline__ u32 pk2(float a, float b) {
  return (u32)f2bf(a) | ((u32)f2bf(b) << 16);
}

#define GLDS(G, L) \
  __builtin_amdgcn_global_load_lds((const __attribute__((address_space(1))) u32*)(G), \
                                   (__attribute__((address_space(3))) u32*)(L), 16, 0, 0)

// ---------------------------------------------------------------------------
// pack_b: B packed in MFMA-fragment order (L2->VGPR direct in the GEMM).
// ---------------------------------------------------------------------------
__global__ void pack_b(const float* __restrict__ coeffs,
                       const float* __restrict__ bw,
                       char* __restrict__ Bp) {
  __shared__ float stage[64][56];
  const int tid = threadIdx.x;
  const int q = tid & 3, g = tid >> 2;
  const int id = blockIdx.x * 64 + g;          // (col, s) pair
  const int col = id >> 7, s = id & 127;
  const float* cbase = coeffs + ((size_t)col * IN_DIM + s * 4) * 13;
#pragma unroll
  for (int j = 0; j < 3; ++j) {
    int ch = q + j * 4;
    float4 v = *(const float4*)(cbase + ch * 4);
    stage[g][ch * 4 + 0] = v.x; stage[g][ch * 4 + 1] = v.y;
    stage[g][ch * 4 + 2] = v.z; stage[g][ch * 4 + 3] = v.w;
  }
  if (q == 0) {
    float4 v = *(const float4*)(cbase + 48);
    stage[g][48] = v.x; stage[g][49] = v.y; stage[g][50] = v.z; stage[g][51] = v.w;
  }
  if (q == 1) {
    float4 v = *(const float4*)(bw + (size_t)col * IN_DIM + s * 4);
    stage[g][52] = v.x; stage[g][53] = v.y; stage[g][54] = v.z; stage[g][55] = v.w;
  }
  __syncthreads();
  const int nbp = col >> 7, cb = (col >> 4) & 7, cl = col & 15;
  char* base = Bp + (((size_t)(nbp * 128 + s) * 8 + cb) * 2) * 1024;
#pragma unroll
  for (int r = 0; r < 2; ++r) {
    int idx = q * 2 + r;
    int h = idx & 1;
    int dd = idx >> 1;              // dim-in-step 0..3
    int ks = dd >> 1;
    const float* sf = &stage[g][dd * 13];
    float w = stage[g][52 + dd];
    u16 hh[8];
#pragma unroll
    for (int c = 0; c < 8; ++c) {
      int slot = h * 8 + c;
      float v = slot < 13 ? sf[slot] : (slot < 15 ? w : 0.0f);
      hh[c] = bfr(v);
    }
    u32x4 o;
    o.x = (u32)hh[0] | ((u32)hh[1] << 16);
    o.y = (u32)hh[2] | ((u32)hh[3] << 16);
    o.z = (u32)hh[4] | ((u32)hh[5] << 16);
    o.w = (u32)hh[6] | ((u32)hh[7] << 16);
    int lanei = cl + 16 * (2 * (dd & 1) + h);
    *(u32x4*)(base + (size_t)ks * 1024 + lanei * 16) = o;
  }
}

// ---------------------------------------------------------------------------
// A expansion: one x -> 16 bf16 K-slots as two swizzled ds_write_b128.
// ---------------------------------------------------------------------------
__device__ __forceinline__ void expandA(float xv, char* rb, u32 swz, u32 k0) {
  float xc = fminf(fmaxf(xv, -0.9999f), 0.9999f);
  float tp = __fmaf_rn(xc, 2.5f, 3.0f);
  float fj = floorf(tp);
  int jl = (int)fj;  // 0..5
  float u = tp - fj;
  float u2 = u * u, u3 = u2 * u;
  float vv = 1.0f - u;
  float b0 = vv * vv * vv * (1.0f / 6.0f);
  float b3 = u3 * (1.0f / 6.0f);
  float b1 = __fmaf_rn(0.5f, u3, __fmaf_rn(u2, -1.0f, 2.0f / 3.0f));
  float b2 = 1.0f - b0 - b1 - b3;
  float e = __expf(-xv);
  float sg = __fdividef(xv, 1.0f + e);
  u16 sh = bfr(sg);
  float shf = __builtin_bit_cast(float, ((u32)sh) << 16);
  u16 sl = bfr(sg - shf);
  u32 pk01 = (u32)bfr(b0) | ((u32)bfr(b1) << 16);
  u32 pk23 = (u32)bfr(b2) | ((u32)bfr(b3) << 16);
  u64 v = (u64)pk01 | (((u64)pk23) << 32);
  int sstart = jl + 2;       // 2..7
  int qa = sstart >> 2;
  int shn = (sstart & 3) << 4;
  u64 lo = v << shn;
  u64 hi = shn ? (v >> (64 - shn)) : 0ull;
  u64 q0 = qa ? 0ull : lo;
  u64 q1 = qa ? lo : hi;
  u64 q2 = qa ? hi : 0ull;
  u64 q3 = (u64)(((u32)sh) << 16) | (((u64)(u32)sl) << 32);
  u32x4 c0, c1;
  c0.x = (u32)q0; c0.y = (u32)(q0 >> 32); c0.z = (u32)q1; c0.w = (u32)(q1 >> 32);
  c1.x = (u32)q2; c1.y = (u32)(q2 >> 32); c1.z = (u32)q3; c1.w = (u32)(q3 >> 32);
  *(u32x4*)(rb + ((k0 ^ swz) << 4)) = c0;
  *(u32x4*)(rb + (((k0 + 1u) ^ swz) << 4)) = c1;
}

// ---------------------------------------------------------------------------
// Main GEMM, wave-specialized + LDS-staged x (3-deep chunk ring):
//   waves 0-7  = COMPUTE: ds_read(A) + reg-dbuf B(L2) + MFMA.
//   waves 8-11 = EXPAND: x via global_load_lds, 16KB chunks (8 steps each),
//                3-deep ring (chunk c -> slot c%3: overwrite target's last
//                read is 3 steps BEFORE the issue -> barrier-ordered, no
//                race). Counted vmcnt(4) once per chunk; tail vmcnt(0) for
//                the final chunks. ZERO per-step vmcnt waits.
// Barriers drain ONLY lgkmcnt.
// ---------------------------------------------------------------------------
__launch_bounds__(768, 3)
__global__ void kan_gemm(const float* __restrict__ x,
                         const char* __restrict__ Bp,
                         float* __restrict__ out) {
  __shared__ __align__(16) char smem[98304];  // A-ring 3x16KB | x-ring 3x16KB

  const int tid = threadIdx.x;
  const int lane = tid & 63;
  const int wid = tid >> 6;
  const bool isC = (wid < 8);

  const int kt = wid >> 2;             // 0/1 (compute)
  const int wm = (wid >> 1) & 1, wn = wid & 1;
  const int lrow = lane & 15, lkg = lane >> 4;

  int s0 = blockIdx.x;
  int xcd = s0 & 7;
  int nb = xcd >> 1;                   // XCD pair owns one 2MB B panel in L2
  int mb = ((s0 >> 3) << 1) | (xcd & 1);  // 0..63

  // expansion decomposition: 256 threads; thread owns rows (erow, erow+64), dim-slot ad
  const int te = tid & 255;
  const int erow = te >> 2;            // 0..63
  const int ad = te & 3;
  const u32 aswz = (u32)(erow & 7);
  const u32 ak0 = (u32)(ad * 2);
  const float* xpa = x + (size_t)(mb * 128 + erow) * IN_DIM + ad;
  const float* xpb = xpa + (size_t)64 * IN_DIM;

  // x-stage constants (expansion waves)
  char* xs = smem + 49152;
  const int ew = wid - 8;                       // 0..3
  const int grb = mb * 128 + ew * 32 + (lane >> 3);  // staged row for this lane
  const int g2 = (lane & 7) ^ (lane >> 3);           // swizzled dim-group
  const u32 xrd = (u32)(ad * 4);

  const char* bptr = Bp + (((size_t)(nb * 128) * 8 + wn * 4) * 2 + kt) * 1024 + (size_t)lane * 16;

  f32x4 acc[4][4];
#pragma unroll
  for (int i = 0; i < 4; ++i)
#pragma unroll
    for (int j = 0; j < 4; ++j) acc[i][j] = (f32x4){0.f, 0.f, 0.f, 0.f};

  u32x4 bA[4], bB[4];
  char* r0 = smem;            // step s
  char* r1 = smem + 16384;    // step s+1
  char* r2 = smem + 32768;    // write buf (step s+2)

  if (isC) {
#pragma unroll
    for (int fn = 0; fn < 4; ++fn)
      bA[fn] = *(const u32x4*)(bptr + fn * 2048);
  } else {
    // stage x chunks 0,1 (dims 0..63) into slots 0,1
#pragma unroll
    for (int c = 0; c < 2; ++c)
#pragma unroll
      for (int k = 0; k < 4; ++k) {
        const float* ga = x + (size_t)(grb + k * 8) * IN_DIM + c * 32 + g2 * 4;
        GLDS(ga, xs + c * 16384 + ((ew * 4 + k) << 10));
      }
    // expand steps 0,1 directly from global x
    expandA(xpa[0], r0 + erow * 128, aswz, ak0);
    expandA(xpb[0], r0 + (erow + 64) * 128, aswz, ak0);
    expandA(xpa[4], r1 + erow * 128, aswz, ak0);
    expandA(xpb[4], r1 + (erow + 64) * 128, aswz, ak0);
  }
  __syncthreads();   // full drain once (x chunks 0,1 visible to all)

  const u32 asl = (((u32)(kt * 4) | (u32)lkg) ^ (u32)(lrow & 7)) << 4;

  // S = current compute step. Compute: MFMA(S), issue B(S+1).
  // Expand: at chunk-start steps stage chunk S/8+2 into slot (c%3) with
  // counted vmcnt (guarantees chunk S/8+1 complete before its first read,
  // cross-wave via the barrier); read x(S+2) from its slot; expand into ring.
#define STEP(S, RB, WB, BCUR, BNXT)                                            \
  {                                                                            \
    if (isC) {                                                                 \
      bf16x8 af[4];                                                            \
      const char* arb = (RB) + (wm * 64 + lrow) * 128;                         \
      _Pragma("unroll")                                                        \
      for (int fm = 0; fm < 4; ++fm)                                           \
        af[fm] = __builtin_bit_cast(bf16x8,                                    \
            *(const u32x4*)(arb + fm * 2048 + asl));                           \
      int sl_ = (S) + 1 < 128 ? (S) + 1 : 127;                                 \
      _Pragma("unroll")                                                        \
      for (int fn = 0; fn < 4; ++fn)                                           \
        BNXT[fn] = *(const u32x4*)(bptr + (size_t)sl_ * 16384 + fn * 2048);    \
      __builtin_amdgcn_s_setprio(1);                                           \
      _Pragma("unroll")                                                        \
      for (int fm = 0; fm < 4; ++fm)                                           \
        _Pragma("unroll")                                                      \
        for (int fn = 0; fn < 4; ++fn)                                         \
          acc[fm][fn] = __builtin_amdgcn_mfma_f32_16x16x32_bf16(               \
              af[fm], __builtin_bit_cast(bf16x8, BCUR[fn]), acc[fm][fn],       \
              0, 0, 0);                                                        \
      __builtin_amdgcn_s_setprio(0);                                           \
    } else {                                                                   \
      if (((S) & 7) == 0) {                                                    \
        int c2 = ((S) >> 3) + 2;                                               \
        if (c2 < 16) {                                                         \
          char* xdst = xs + (c2 % 3) * 16384;                                  \
          _Pragma("unroll")                                                    \
          for (int k = 0; k < 4; ++k) {                                        \
            const float* ga = x + (size_t)(grb + k * 8) * IN_DIM + c2 * 32 + g2 * 4; \
            GLDS(ga, xdst + ((ew * 4 + k) << 10));                             \
          }                                                                    \
          asm volatile("s_waitcnt vmcnt(4)" ::: "memory");                     \
        } else {                                                               \
          asm volatile("s_waitcnt vmcnt(0)" ::: "memory");                     \
        }                                                                      \
      }                                                                        \
      if ((S) + 2 < 128) {                                                     \
        int Sp = (S) + 2;                                                      \
        int cc = Sp >> 3, gg = Sp & 7;                                         \
        const char* xb_ = xs + (cc % 3) * 16384;                               \
        u32 xo = ((u32)(gg ^ (erow & 7)) << 4) + xrd;                          \
        float xa = *(const float*)(xb_ + erow * 128 + xo);                     \
        float xv2 = *(const float*)(xb_ + (erow + 64) * 128 + xo);             \
        expandA(xa, (WB) + erow * 128, aswz, ak0);                             \
        expandA(xv2, (WB) + (erow + 64) * 128, aswz, ak0);                     \
      }                                                                        \
      asm volatile("s_waitcnt lgkmcnt(0)" ::: "memory");                       \
    }                                                                          \
    __builtin_amdgcn_s_barrier();                                              \
  }

#pragma unroll 1
  for (int s = 0; s < 128; s += 2) {
    STEP(s, r0, r2, bA, bB)
    STEP(s + 1, r1, r0, bB, bA)
    char* t = r2; r2 = r1; r1 = r0; r0 = t;   // ring rotate
  }

  __syncthreads();  // full drain before smem reuse

  // epilogue: deterministic kt-reduction via LDS (stride 132 floats), +x
  float* red = (float*)smem;
  if (isC && kt == 1) {
#pragma unroll
    for (int fm = 0; fm < 4; ++fm)
#pragma unroll
      for (int fn = 0; fn < 4; ++fn) {
        int rr = wm * 64 + fm * 16 + lkg * 4;
        int cc = wn * 64 + fn * 16 + lrow;
#pragma unroll
        for (int r = 0; r < 4; ++r)
          red[(size_t)(rr + r) * 132 + cc] = acc[fm][fn][r];
      }
  }
  __syncthreads();
  if (isC && kt == 0) {
#pragma unroll
    for (int fm = 0; fm < 4; ++fm)
#pragma unroll
      for (int fn = 0; fn < 4; ++fn) {
        int rr = wm * 64 + fm * 16 + lkg * 4;
        int cc = wn * 64 + fn * 16 + lrow;
        size_t gb = (size_t)(mb * 128 + rr) * IN_DIM + nb * 128 + cc;
#pragma unroll
        for (int r = 0; r < 4; ++r) {
          size_t off = gb + (size_t)r * IN_DIM;
          out[off] = acc[fm][fn][r] + red[(size_t)(rr + r) * 132 + cc] + x[off];
        }
      }
  }
}

// ---------------------------------------------------------------------------
// Fallback (round-1 kernel) if ws too small for B_packed (8MB)
// ---------------------------------------------------------------------------
__device__ __forceinline__ void st_b16(char* rb, u32 swz, u32 k0, int c, u16 v) {
  u32 uc = (u32)c;
  u32 byte = (((k0 + (uc >> 3)) ^ swz) << 4) | ((uc & 7u) << 1);
  *(u16*)(rb + byte) = v;
}

__device__ __forceinline__ void stage_a_fb(char* aT, int row, int d, float xv) {
  char* rb = aT + row * 128;
  u32 swz = (u32)(row & 7);
  float xc = fminf(fmaxf(xv, -0.9999f), 0.9999f);
  float tp = __fmaf_rn(xc, 2.5f, 3.0f);
  float fj = floorf(tp);
  int jl = (int)fj;
  float u = tp - fj;
  float u2 = u * u, u3 = u2 * u;
  float vv = 1.0f - u;
  float b0 = vv * vv * vv * (1.0f / 6.0f);
  float b3 = u3 * (1.0f / 6.0f);
  float b1 = __fmaf_rn(0.5f, u3, __fmaf_rn(u2, -1.0f, 2.0f / 3.0f));
  float b2 = 1.0f - b0 - b1 - b3;
  float e = __expf(-xv);
  float sg = __fdividef(xv, 1.0f + e);
  u16 sh = f2bf(sg);
  float shf = __builtin_bit_cast(float, ((u32)sh) << 16);
  u16 slo = f2bf(sg - shf);
  u32 k0 = (u32)d * 2u;
  u32x4 z = {0u, 0u, 0u, 0u};
  *(u32x4*)(rb + ((k0 ^ swz) << 4)) = z;
  u32x4 z2 = {0u, 0u, ((u32)sh) << 16, (u32)slo};
  *(u32x4*)(rb + (((k0 + 1u) ^ swz) << 4)) = z2;
  st_b16(rb, swz, k0, jl + 2, f2bf(b0));
  st_b16(rb, swz, k0, jl + 3, f2bf(b1));
  st_b16(rb, swz, k0, jl + 4, f2bf(b2));
  st_b16(rb, swz, k0, jl + 5, f2bf(b3));
}

__launch_bounds__(512, 2)
__global__ void kan_fused(const float* __restrict__ x,
                          const float* __restrict__ coeffs,
                          const float* __restrict__ bw,
                          float* __restrict__ out) {
  __shared__ __align__(16) char smem[65536];
  const int tid = threadIdx.x;
  const int lane = tid & 63;
  const int wid = tid >> 6;
  const int team = wid >> 2;
  const int wm = (wid >> 1) & 1;
  const int wn = wid & 1;
  const int m0 = wm * 64, n0 = wn * 64;
  const int lrow = lane & 15;
  const int lkg = lane >> 4;
  int s = blockIdx.x;
  int xcd = s & 7;
  int nb = xcd >> 1;
  int mb = (s >> 3) | ((xcd & 1) << 5);
  const int t = tid & 255;
  const int arow = t >> 1;
  const int h = t & 1;
  char* aT = smem + team * 16384;
  char* bT = smem + 32768 + team * 16384;
  const int dim0 = team * 256;
  const float* xptr = x + (size_t)(mb * 128 + arow) * IN_DIM + dim0 + 2 * h;
  const float* cptr = coeffs + ((size_t)((nb * 128 + arow) * IN_DIM) + dim0) * 13 + 26 * h;
  const float* wptr = bw + (size_t)(nb * 128 + arow) * IN_DIM + dim0 + 2 * h;
  f32x4 acc[4][4];
#pragma unroll
  for (int i = 0; i < 4; ++i)
#pragma unroll
    for (int j = 0; j < 4; ++j) acc[i][j] = (f32x4){0.f, 0.f, 0.f, 0.f};
  float2 xv, wv;
  float2 cv0, cv1, cv2, cv3, cv4, cv5, cv6, cv7, cv8, cv9, cv10, cv11, cv12;
#define PREFETCH(STP)                                                     \
  {                                                                       \
    const float* cp_ = cptr + (STP) * 52;                                 \
    xv = *(const float2*)(xptr + (STP) * 4);                              \
    wv = *(const float2*)(wptr + (STP) * 4);                              \
    cv0 = *(const float2*)(cp_ + 0);   cv1 = *(const float2*)(cp_ + 2);   \
    cv2 = *(const float2*)(cp_ + 4);   cv3 = *(const float2*)(cp_ + 6);   \
    cv4 = *(const float2*)(cp_ + 8);   cv5 = *(const float2*)(cp_ + 10);  \
    cv6 = *(const float2*)(cp_ + 12);  cv7 = *(const float2*)(cp_ + 14);  \
    cv8 = *(const float2*)(cp_ + 16);  cv9 = *(const float2*)(cp_ + 18);  \
    cv10 = *(const float2*)(cp_ + 20); cv11 = *(const float2*)(cp_ + 22); \
    cv12 = *(const float2*)(cp_ + 24);                                    \
  }
  PREFETCH(0)
  for (int st = 0; st < 64; ++st) {
    stage_a_fb(aT, arow, 2 * h + 0, xv.x);
    stage_a_fb(aT, arow, 2 * h + 1, xv.y);
    {
      char* rb = bT + arow * 128;
      u32 swz = (u32)(arow & 7);
      u32 k0 = (u32)(2 * h) * 2u;
      u32x4 lo, hi;
      lo.x = pk2(cv0.x, cv0.y); lo.y = pk2(cv1.x, cv1.y);
      lo.z = pk2(cv2.x, cv2.y); lo.w = pk2(cv3.x, cv3.y);
      hi.x = pk2(cv4.x, cv4.y); hi.y = pk2(cv5.x, cv5.y);
      {
        u16 wb = f2bf(wv.x);
        hi.z = (u32)f2bf(cv6.x) | ((u32)wb << 16);
        hi.w = (u32)wb;
      }
      *(u32x4*)(rb + ((k0 ^ swz) << 4)) = lo;
      *(u32x4*)(rb + (((k0 + 1u) ^ swz) << 4)) = hi;
      lo.x = pk2(cv6.y, cv7.x);  lo.y = pk2(cv7.y, cv8.x);
      lo.z = pk2(cv8.y, cv9.x);  lo.w = pk2(cv9.y, cv10.x);
      hi.x = pk2(cv10.y, cv11.x); hi.y = pk2(cv11.y, cv12.x);
      {
        u16 wb = f2bf(wv.y);
        hi.z = (u32)f2bf(cv12.y) | ((u32)wb << 16);
        hi.w = (u32)wb;
      }
      *(u32x4*)(rb + (((k0 + 2u) ^ swz) << 4)) = lo;
      *(u32x4*)(rb + (((k0 + 3u) ^ swz) << 4)) = hi;
    }
    __syncthreads();
    if (st != 63) { PREFETCH(st + 1) }
    {
      const char* arb = aT + (m0 + lrow) * 128;
      const char* brb = bT + (n0 + lrow) * 128;
      u32 rsw = (u32)(lrow & 7);
#pragma unroll
      for (int ks = 0; ks < 2; ++ks) {
        u32 sl2 = (((u32)(ks * 4) | (u32)lkg) ^ rsw) << 4;
        bf16x8 af[4], bfr2[4];
#pragma unroll
        for (int fm = 0; fm < 4; ++fm)
          af[fm] = __builtin_bit_cast(bf16x8, *(const u32x4*)(arb + fm * 2048 + sl2));
#pragma unroll
        for (int fn = 0; fn < 4; ++fn)
          bfr2[fn] = __builtin_bit_cast(bf16x8, *(const u32x4*)(brb + fn * 2048 + sl2));
#pragma unroll
        for (int fm = 0; fm < 4; ++fm)
#pragma unroll
          for (int fn = 0; fn < 4; ++fn)
            acc[fm][fn] = __builtin_amdgcn_mfma_f32_16x16x32_bf16(
                af[fm], bfr2[fn], acc[fm][fn], 0, 0, 0);
      }
    }
    __syncthreads();
  }
  float* red = (float*)smem;
  if (team == 1) {
#pragma unroll
    for (int fm = 0; fm < 4; ++fm)
#pragma unroll
      for (int fn = 0; fn < 4; ++fn) {
        int rr = m0 + fm * 16 + lkg * 4;
        int cc = n0 + fn * 16 + lrow;
#pragma unroll
        for (int r = 0; r < 4; ++r) red[(rr + r) * 128 + cc] = acc[fm][fn][r];
      }
  }
  __syncthreads();
  if (team == 0) {
#pragma unroll
    for (int fm = 0; fm < 4; ++fm)
#pragma unroll
      for (int fn = 0; fn < 4; ++fn) {
        int rr = m0 + fm * 16 + lkg * 4;
        int ccol = n0 + fn * 16 + lrow;
        int grow = mb * 128 + rr;
        int gcol = nb * 128 + ccol;
#pragma unroll
        for (int r = 0; r < 4; ++r) {
          float v = acc[fm][fn][r] + red[(rr + r) * 128 + ccol] +
                    x[(size_t)(grow + r) * IN_DIM + gcol];
          out[(size_t)(grow + r) * IN_DIM + gcol] = v;
        }
      }
  }
}

extern "C" void kernel_launch(void* const* d_in, const int* in_sizes, int n_in,
                              void* d_out, int out_size, void* d_ws, size_t ws_size,
                              hipStream_t stream) {
  const float* x = (const float*)d_in[0];
  const float* coeffs = (const float*)d_in[1];
  const float* bw = (const float*)d_in[2];
  float* out = (float*)d_out;
  if (ws_size >= (size_t)512 * 16384) {  // 8 MB for B_packed
    char* Bp = (char*)d_ws;
    hipLaunchKernelGGL(pack_b, dim3(1024), dim3(256), 0, stream, coeffs, bw, Bp);
    hipLaunchKernelGGL(kan_gemm, dim3(256), dim3(768), 0, stream, x, Bp, out);
  } else {
    hipLaunchKernelGGL(kan_fused, dim3(256), dim3(512), 0, stream, x, coeffs, bw, out);
  }
}

// Round 10
// 99.454 us; speedup vs baseline: 1.1341x; 1.1341x over previous
//
#include <hip/hip_runtime.h>
#include <stdint.h>

typedef unsigned int u32;
typedef unsigned short u16;
typedef unsigned long long u64;
typedef __bf16 bf16x8 __attribute__((ext_vector_type(8)));
typedef float f32x4 __attribute__((ext_vector_type(4)));
typedef u32 u32x4 __attribute__((ext_vector_type(4)));

#define IN_DIM 512

__device__ __forceinline__ u16 bfr(float f) {
  __bf16 h = (__bf16)f;
  return __builtin_bit_cast(u16, h);
}
__device__ __forceinline__ u16 f2bf(float f) {
  u32 u = __builtin_bit_cast(u32, f);
  u += 0x7fffu + ((u >> 16) & 1u);
  return (u16)(u >> 16);
}
__device__ __forceinline__ u32 pk2(float a, float b) {
  return (u32)f2bf(a) | ((u32)f2bf(b) << 16);
}

// ---------------------------------------------------------------------------
// pack_b: B packed in MFMA-fragment order (L2->VGPR direct in the GEMM).
// Chunk(nbp, s, cb, ks) = 64 lanes x 16B; lane l holds
//   col = nbp*128 + cb*16 + (l&15), kexp = s*64 + ks*32 + (l>>4)*8 .. +7
// Per (col,dim) 16 slots: 0..12 coeffs, 13=W, 14=W, 15=0.
// ---------------------------------------------------------------------------
__global__ void pack_b(const float* __restrict__ coeffs,
                       const float* __restrict__ bw,
                       char* __restrict__ Bp) {
  __shared__ float stage[64][56];
  const int tid = threadIdx.x;
  const int q = tid & 3, g = tid >> 2;
  const int id = blockIdx.x * 64 + g;          // (col, s) pair
  const int col = id >> 7, s = id & 127;
  const float* cbase = coeffs + ((size_t)col * IN_DIM + s * 4) * 13;
#pragma unroll
  for (int j = 0; j < 3; ++j) {
    int ch = q + j * 4;
    float4 v = *(const float4*)(cbase + ch * 4);
    stage[g][ch * 4 + 0] = v.x; stage[g][ch * 4 + 1] = v.y;
    stage[g][ch * 4 + 2] = v.z; stage[g][ch * 4 + 3] = v.w;
  }
  if (q == 0) {
    float4 v = *(const float4*)(cbase + 48);
    stage[g][48] = v.x; stage[g][49] = v.y; stage[g][50] = v.z; stage[g][51] = v.w;
  }
  if (q == 1) {
    float4 v = *(const float4*)(bw + (size_t)col * IN_DIM + s * 4);
    stage[g][52] = v.x; stage[g][53] = v.y; stage[g][54] = v.z; stage[g][55] = v.w;
  }
  __syncthreads();
  const int nbp = col >> 7, cb = (col >> 4) & 7, cl = col & 15;
  char* base = Bp + (((size_t)(nbp * 128 + s) * 8 + cb) * 2) * 1024;
#pragma unroll
  for (int r = 0; r < 2; ++r) {
    int idx = q * 2 + r;
    int h = idx & 1;
    int dd = idx >> 1;              // dim-in-step 0..3
    int ks = dd >> 1;
    const float* sf = &stage[g][dd * 13];
    float w = stage[g][52 + dd];
    u16 hh[8];
#pragma unroll
    for (int c = 0; c < 8; ++c) {
      int slot = h * 8 + c;
      float v = slot < 13 ? sf[slot] : (slot < 15 ? w : 0.0f);
      hh[c] = bfr(v);
    }
    u32x4 o;
    o.x = (u32)hh[0] | ((u32)hh[1] << 16);
    o.y = (u32)hh[2] | ((u32)hh[3] << 16);
    o.z = (u32)hh[4] | ((u32)hh[5] << 16);
    o.w = (u32)hh[6] | ((u32)hh[7] << 16);
    int lanei = cl + 16 * (2 * (dd & 1) + h);
    *(u32x4*)(base + (size_t)ks * 1024 + lanei * 16) = o;
  }
}

// ---------------------------------------------------------------------------
// A expansion: one x -> 16 bf16 K-slots as two swizzled ds_write_b128.
// ---------------------------------------------------------------------------
__device__ __forceinline__ void expandA(float xv, char* rb, u32 swz, u32 k0) {
  float xc = fminf(fmaxf(xv, -0.9999f), 0.9999f);
  float tp = __fmaf_rn(xc, 2.5f, 3.0f);
  float fj = floorf(tp);
  int jl = (int)fj;  // 0..5
  float u = tp - fj;
  float u2 = u * u, u3 = u2 * u;
  float vv = 1.0f - u;
  float b0 = vv * vv * vv * (1.0f / 6.0f);
  float b3 = u3 * (1.0f / 6.0f);
  float b1 = __fmaf_rn(0.5f, u3, __fmaf_rn(u2, -1.0f, 2.0f / 3.0f));
  float b2 = 1.0f - b0 - b1 - b3;
  float e = __expf(-xv);
  float sg = __fdividef(xv, 1.0f + e);
  u16 sh = bfr(sg);
  float shf = __builtin_bit_cast(float, ((u32)sh) << 16);
  u16 sl = bfr(sg - shf);
  u32 pk01 = (u32)bfr(b0) | ((u32)bfr(b1) << 16);
  u32 pk23 = (u32)bfr(b2) | ((u32)bfr(b3) << 16);
  u64 v = (u64)pk01 | (((u64)pk23) << 32);
  int sstart = jl + 2;       // 2..7
  int qa = sstart >> 2;
  int shn = (sstart & 3) << 4;
  u64 lo = v << shn;
  u64 hi = shn ? (v >> (64 - shn)) : 0ull;
  u64 q0 = qa ? 0ull : lo;
  u64 q1 = qa ? lo : hi;
  u64 q2 = qa ? hi : 0ull;
  u64 q3 = (u64)(((u32)sh) << 16) | (((u64)(u32)sl) << 32);
  u32x4 c0, c1;
  c0.x = (u32)q0; c0.y = (u32)(q0 >> 32); c0.z = (u32)q1; c0.w = (u32)(q1 >> 32);
  c1.x = (u32)q2; c1.y = (u32)(q2 >> 32); c1.z = (u32)q3; c1.w = (u32)(q3 >> 32);
  *(u32x4*)(rb + ((k0 ^ swz) << 4)) = c0;
  *(u32x4*)(rb + (((k0 + 1u) ^ swz) << 4)) = c1;
}

// ---------------------------------------------------------------------------
// Main GEMM, wave-specialized + A-FRAGMENT PREFETCH:
//   waves 0-7  = COMPUTE: issue ds_read of A(S+1) frags at step-S top (A(S+1)
//                is guaranteed complete in the ring: written during S-1,
//                published at that barrier) -> MFMA(S) runs on registers
//                loaded LAST step. The ~600cy LDS-read phase now hides under
//                the ~620cy MFMA phase instead of serializing in front of it.
//   waves 8-11 = EXPAND: direct global x (2-step reg lookahead) + spline/silu
//                VALU + ds_write into ring-3.
// Barriers drain ONLY lgkmcnt on the expansion side; compute side none.
// ---------------------------------------------------------------------------
__launch_bounds__(768, 3)
__global__ void kan_gemm(const float* __restrict__ x,
                         const char* __restrict__ Bp,
                         float* __restrict__ out) {
  __shared__ __align__(16) char smem[67584];  // ring 3x16KB | red 128x132 f32

  const int tid = threadIdx.x;
  const int lane = tid & 63;
  const int wid = tid >> 6;
  const bool isC = (wid < 8);

  const int kt = wid >> 2;             // 0/1 (compute)
  const int wm = (wid >> 1) & 1, wn = wid & 1;
  const int lrow = lane & 15, lkg = lane >> 4;

  int s0 = blockIdx.x;
  int xcd = s0 & 7;
  int nb = xcd >> 1;                   // XCD pair owns one 2MB B panel in L2
  int mb = ((s0 >> 3) << 1) | (xcd & 1);  // 0..63

  // expand-wave decomposition: 256 threads; thread owns rows (erow, erow+64), dim ad
  const int te = tid & 255;
  const int erow = te >> 2;            // 0..63
  const int ad = te & 3;
  const u32 aswz = (u32)(erow & 7);
  const u32 ak0 = (u32)(ad * 2);
  const float* xpa = x + (size_t)(mb * 128 + erow) * IN_DIM + ad;
  const float* xpb = xpa + (size_t)64 * IN_DIM;

  const char* bptr = Bp + (((size_t)(nb * 128) * 8 + wn * 4) * 2 + kt) * 1024 + (size_t)lane * 16;

  f32x4 acc[4][4];
#pragma unroll
  for (int i = 0; i < 4; ++i)
#pragma unroll
    for (int j = 0; j < 4; ++j) acc[i][j] = (f32x4){0.f, 0.f, 0.f, 0.f};

  u32x4 bA[4], bB[4];
  u32x4 afA[4], afB[4];
  char* r0 = smem;            // step s
  char* r1 = smem + 16384;    // step s+1
  char* r2 = smem + 32768;    // write buf (step s+2)

  float xa1 = 0.f, xa2 = 0.f, xb1 = 0.f, xb2 = 0.f;
  if (isC) {
#pragma unroll
    for (int fn = 0; fn < 4; ++fn)
      bA[fn] = *(const u32x4*)(bptr + fn * 2048);
  } else {
    // prologue: fill ring slots for steps 0 and 1; x lookahead for 2,3
    expandA(xpa[0], r0 + erow * 128, aswz, ak0);
    expandA(xpb[0], r0 + (erow + 64) * 128, aswz, ak0);
    expandA(xpa[4], r1 + erow * 128, aswz, ak0);
    expandA(xpb[4], r1 + (erow + 64) * 128, aswz, ak0);
    xa1 = xpa[8];  xb1 = xpb[8];    // x(step 2)
    xa2 = xpa[12]; xb2 = xpb[12];   // x(step 3)
  }
  __syncthreads();   // one-time full drain (A(0), A(1) visible)

  const u32 asl = (((u32)(kt * 4) | (u32)lkg) ^ (u32)(lrow & 7)) << 4;

  // prologue compute: load A(0) fragments into afA
  if (isC) {
    const char* arb0 = r0 + (wm * 64 + lrow) * 128;
#pragma unroll
    for (int fm = 0; fm < 4; ++fm)
      afA[fm] = *(const u32x4*)(arb0 + fm * 2048 + asl);
  }

  // S = current compute step.
  // Compute: prefetch A(S+1) frags from RBN (already complete in ring),
  //          issue B(S+1), MFMA(S) with AFC/BCUR loaded last step.
  // Expand: expand(S+2) into WB from regs, load x(S+4), lgkm(0).
#define STEP(S, RBN, WB, BCUR, BNXT, AFC, AFN)                                 \
  {                                                                            \
    if (isC) {                                                                 \
      const char* arbn = (RBN) + (wm * 64 + lrow) * 128;                       \
      _Pragma("unroll")                                                        \
      for (int fm = 0; fm < 4; ++fm)                                           \
        AFN[fm] = *(const u32x4*)(arbn + fm * 2048 + asl);                     \
      int sl_ = (S) + 1 < 128 ? (S) + 1 : 127;                                 \
      _Pragma("unroll")                                                        \
      for (int fn = 0; fn < 4; ++fn)                                           \
        BNXT[fn] = *(const u32x4*)(bptr + (size_t)sl_ * 16384 + fn * 2048);    \
      __builtin_amdgcn_s_setprio(1);                                           \
      _Pragma("unroll")                                                        \
      for (int fm = 0; fm < 4; ++fm)                                           \
        _Pragma("unroll")                                                      \
        for (int fn = 0; fn < 4; ++fn)                                         \
          acc[fm][fn] = __builtin_amdgcn_mfma_f32_16x16x32_bf16(               \
              __builtin_bit_cast(bf16x8, AFC[fm]),                             \
              __builtin_bit_cast(bf16x8, BCUR[fn]), acc[fm][fn], 0, 0, 0);     \
      __builtin_amdgcn_s_setprio(0);                                           \
    } else {                                                                   \
      if ((S) + 2 < 128) {                                                     \
        expandA(xa1, (WB) + erow * 128, aswz, ak0);                            \
        expandA(xb1, (WB) + (erow + 64) * 128, aswz, ak0);                     \
      }                                                                        \
      int xi = ((S) + 4 < 128 ? (S) + 4 : 127) * 4;                            \
      float na = xpa[xi], nbv = xpb[xi];                                       \
      xa1 = xa2; xa2 = na; xb1 = xb2; xb2 = nbv;                               \
      asm volatile("s_waitcnt lgkmcnt(0)" ::: "memory");                       \
    }                                                                          \
    __builtin_amdgcn_s_barrier();                                              \
  }

#pragma unroll 1
  for (int s = 0; s < 128; s += 2) {
    STEP(s, r1, r2, bA, bB, afA, afB)      // MFMA(s) w/ afA; prefetch A(s+1)
    STEP(s + 1, r2, r0, bB, bA, afB, afA)  // MFMA(s+1) w/ afB; prefetch A(s+2)
    char* t = r2; r2 = r1; r1 = r0; r0 = t;   // ring rotate
  }

  __syncthreads();  // full drain before smem reuse

  // epilogue: deterministic kt-reduction via LDS (stride 132 floats), +x
  float* red = (float*)smem;
  if (isC && kt == 1) {
#pragma unroll
    for (int fm = 0; fm < 4; ++fm)
#pragma unroll
      for (int fn = 0; fn < 4; ++fn) {
        int rr = wm * 64 + fm * 16 + lkg * 4;
        int cc = wn * 64 + fn * 16 + lrow;
#pragma unroll
        for (int r = 0; r < 4; ++r)
          red[(size_t)(rr + r) * 132 + cc] = acc[fm][fn][r];
      }
  }
  __syncthreads();
  if (isC && kt == 0) {
#pragma unroll
    for (int fm = 0; fm < 4; ++fm)
#pragma unroll
      for (int fn = 0; fn < 4; ++fn) {
        int rr = wm * 64 + fm * 16 + lkg * 4;
        int cc = wn * 64 + fn * 16 + lrow;
        size_t gb = (size_t)(mb * 128 + rr) * IN_DIM + nb * 128 + cc;
#pragma unroll
        for (int r = 0; r < 4; ++r) {
          size_t off = gb + (size_t)r * IN_DIM;
          out[off] = acc[fm][fn][r] + red[(size_t)(rr + r) * 132 + cc] + x[off];
        }
      }
  }
}

// ---------------------------------------------------------------------------
// Fallback (round-1 kernel) if ws too small for B_packed (8MB)
// ---------------------------------------------------------------------------
__device__ __forceinline__ void st_b16(char* rb, u32 swz, u32 k0, int c, u16 v) {
  u32 uc = (u32)c;
  u32 byte = (((k0 + (uc >> 3)) ^ swz) << 4) | ((uc & 7u) << 1);
  *(u16*)(rb + byte) = v;
}

__device__ __forceinline__ void stage_a_fb(char* aT, int row, int d, float xv) {
  char* rb = aT + row * 128;
  u32 swz = (u32)(row & 7);
  float xc = fminf(fmaxf(xv, -0.9999f), 0.9999f);
  float tp = __fmaf_rn(xc, 2.5f, 3.0f);
  float fj = floorf(tp);
  int jl = (int)fj;
  float u = tp - fj;
  float u2 = u * u, u3 = u2 * u;
  float vv = 1.0f - u;
  float b0 = vv * vv * vv * (1.0f / 6.0f);
  float b3 = u3 * (1.0f / 6.0f);
  float b1 = __fmaf_rn(0.5f, u3, __fmaf_rn(u2, -1.0f, 2.0f / 3.0f));
  float b2 = 1.0f - b0 - b1 - b3;
  float e = __expf(-xv);
  float sg = __fdividef(xv, 1.0f + e);
  u16 sh = f2bf(sg);
  float shf = __builtin_bit_cast(float, ((u32)sh) << 16);
  u16 slo = f2bf(sg - shf);
  u32 k0 = (u32)d * 2u;
  u32x4 z = {0u, 0u, 0u, 0u};
  *(u32x4*)(rb + ((k0 ^ swz) << 4)) = z;
  u32x4 z2 = {0u, 0u, ((u32)sh) << 16, (u32)slo};
  *(u32x4*)(rb + (((k0 + 1u) ^ swz) << 4)) = z2;
  st_b16(rb, swz, k0, jl + 2, f2bf(b0));
  st_b16(rb, swz, k0, jl + 3, f2bf(b1));
  st_b16(rb, swz, k0, jl + 4, f2bf(b2));
  st_b16(rb, swz, k0, jl + 5, f2bf(b3));
}

__launch_bounds__(512, 2)
__global__ void kan_fused(const float* __restrict__ x,
                          const float* __restrict__ coeffs,
                          const float* __restrict__ bw,
                          float* __restrict__ out) {
  __shared__ __align__(16) char smem[65536];
  const int tid = threadIdx.x;
  const int lane = tid & 63;
  const int wid = tid >> 6;
  const int team = wid >> 2;
  const int wm = (wid >> 1) & 1;
  const int wn = wid & 1;
  const int m0 = wm * 64, n0 = wn * 64;
  const int lrow = lane & 15;
  const int lkg = lane >> 4;
  int s = blockIdx.x;
  int xcd = s & 7;
  int nb = xcd >> 1;
  int mb = (s >> 3) | ((xcd & 1) << 5);
  const int t = tid & 255;
  const int arow = t >> 1;
  const int h = t & 1;
  char* aT = smem + team * 16384;
  char* bT = smem + 32768 + team * 16384;
  const int dim0 = team * 256;
  const float* xptr = x + (size_t)(mb * 128 + arow) * IN_DIM + dim0 + 2 * h;
  const float* cptr = coeffs + ((size_t)((nb * 128 + arow) * IN_DIM) + dim0) * 13 + 26 * h;
  const float* wptr = bw + (size_t)(nb * 128 + arow) * IN_DIM + dim0 + 2 * h;
  f32x4 acc[4][4];
#pragma unroll
  for (int i = 0; i < 4; ++i)
#pragma unroll
    for (int j = 0; j < 4; ++j) acc[i][j] = (f32x4){0.f, 0.f, 0.f, 0.f};
  float2 xv, wv;
  float2 cv0, cv1, cv2, cv3, cv4, cv5, cv6, cv7, cv8, cv9, cv10, cv11, cv12;
#define PREFETCH(STP)                                                     \
  {                                                                       \
    const float* cp_ = cptr + (STP) * 52;                                 \
    xv = *(const float2*)(xptr + (STP) * 4);                              \
    wv = *(const float2*)(wptr + (STP) * 4);                              \
    cv0 = *(const float2*)(cp_ + 0);   cv1 = *(const float2*)(cp_ + 2);   \
    cv2 = *(const float2*)(cp_ + 4);   cv3 = *(const float2*)(cp_ + 6);   \
    cv4 = *(const float2*)(cp_ + 8);   cv5 = *(const float2*)(cp_ + 10);  \
    cv6 = *(const float2*)(cp_ + 12);  cv7 = *(const float2*)(cp_ + 14);  \
    cv8 = *(const float2*)(cp_ + 16);  cv9 = *(const float2*)(cp_ + 18);  \
    cv10 = *(const float2*)(cp_ + 20); cv11 = *(const float2*)(cp_ + 22); \
    cv12 = *(const float2*)(cp_ + 24);                                    \
  }
  PREFETCH(0)
  for (int st = 0; st < 64; ++st) {
    stage_a_fb(aT, arow, 2 * h + 0, xv.x);
    stage_a_fb(aT, arow, 2 * h + 1, xv.y);
    {
      char* rb = bT + arow * 128;
      u32 swz = (u32)(arow & 7);
      u32 k0 = (u32)(2 * h) * 2u;
      u32x4 lo, hi;
      lo.x = pk2(cv0.x, cv0.y); lo.y = pk2(cv1.x, cv1.y);
      lo.z = pk2(cv2.x, cv2.y); lo.w = pk2(cv3.x, cv3.y);
      hi.x = pk2(cv4.x, cv4.y); hi.y = pk2(cv5.x, cv5.y);
      {
        u16 wb = f2bf(wv.x);
        hi.z = (u32)f2bf(cv6.x) | ((u32)wb << 16);
        hi.w = (u32)wb;
      }
      *(u32x4*)(rb + ((k0 ^ swz) << 4)) = lo;
      *(u32x4*)(rb + (((k0 + 1u) ^ swz) << 4)) = hi;
      lo.x = pk2(cv6.y, cv7.x);  lo.y = pk2(cv7.y, cv8.x);
      lo.z = pk2(cv8.y, cv9.x);  lo.w = pk2(cv9.y, cv10.x);
      hi.x = pk2(cv10.y, cv11.x); hi.y = pk2(cv11.y, cv12.x);
      {
        u16 wb = f2bf(wv.y);
        hi.z = (u32)f2bf(cv12.y) | ((u32)wb << 16);
        hi.w = (u32)wb;
      }
      *(u32x4*)(rb + (((k0 + 2u) ^ swz) << 4)) = lo;
      *(u32x4*)(rb + (((k0 + 3u) ^ swz) << 4)) = hi;
    }
    __syncthreads();
    if (st != 63) { PREFETCH(st + 1) }
    {
      const char* arb = aT + (m0 + lrow) * 128;
      const char* brb = bT + (n0 + lrow) * 128;
      u32 rsw = (u32)(lrow & 7);
#pragma unroll
      for (int ks = 0; ks < 2; ++ks) {
        u32 sl2 = (((u32)(ks * 4) | (u32)lkg) ^ rsw) << 4;
        bf16x8 af[4], bfr2[4];
#pragma unroll
        for (int fm = 0; fm < 4; ++fm)
          af[fm] = __builtin_bit_cast(bf16x8, *(const u32x4*)(arb + fm * 2048 + sl2));
#pragma unroll
        for (int fn = 0; fn < 4; ++fn)
          bfr2[fn] = __builtin_bit_cast(bf16x8, *(const u32x4*)(brb + fn * 2048 + sl2));
#pragma unroll
        for (int fm = 0; fm < 4; ++fm)
#pragma unroll
          for (int fn = 0; fn < 4; ++fn)
            acc[fm][fn] = __builtin_amdgcn_mfma_f32_16x16x32_bf16(
                af[fm], bfr2[fn], acc[fm][fn], 0, 0, 0);
      }
    }
    __syncthreads();
  }
  float* red = (float*)smem;
  if (team == 1) {
#pragma unroll
    for (int fm = 0; fm < 4; ++fm)
#pragma unroll
      for (int fn = 0; fn < 4; ++fn) {
        int rr = m0 + fm * 16 + lkg * 4;
        int cc = n0 + fn * 16 + lrow;
#pragma unroll
        for (int r = 0; r < 4; ++r) red[(rr + r) * 128 + cc] = acc[fm][fn][r];
      }
  }
  __syncthreads();
  if (team == 0) {
#pragma unroll
    for (int fm = 0; fm < 4; ++fm)
#pragma unroll
      for (int fn = 0; fn < 4; ++fn) {
        int rr = m0 + fm * 16 + lkg * 4;
        int ccol = n0 + fn * 16 + lrow;
        int grow = mb * 128 + rr;
        int gcol = nb * 128 + ccol;
#pragma unroll
        for (int r = 0; r < 4; ++r) {
          float v = acc[fm][fn][r] + red[(rr + r) * 128 + ccol] +
                    x[(size_t)(grow + r) * IN_DIM + gcol];
          out[(size_t)(grow + r) * IN_DIM + gcol] = v;
        }
      }
  }
}

extern "C" void kernel_launch(void* const* d_in, const int* in_sizes, int n_in,
                              void* d_out, int out_size, void* d_ws, size_t ws_size,
                              hipStream_t stream) {
  const float* x = (const float*)d_in[0];
  const float* coeffs = (const float*)d_in[1];
  const float* bw = (const float*)d_in[2];
  float* out = (float*)d_out;
  if (ws_size >= (size_t)512 * 16384) {  // 8 MB for B_packed
    char* Bp = (char*)d_ws;
    hipLaunchKernelGGL(pack_b, dim3(1024), dim3(256), 0, stream, coeffs, bw, Bp);
    hipLaunchKernelGGL(kan_gemm, dim3(256), dim3(768), 0, stream, x, Bp, out);
  } else {
    hipLaunchKernelGGL(kan_fused, dim3(256), dim3(512), 0, stream, x, coeffs, bw, out);
  }
}

// Round 11
// 89.095 us; speedup vs baseline: 1.2660x; 1.1163x over previous
//
#include <hip/hip_runtime.h>
#include <stdint.h>

typedef unsigned int u32;
typedef unsigned short u16;
typedef unsigned long long u64;
typedef __bf16 bf16x8 __attribute__((ext_vector_type(8)));
typedef float f32x4 __attribute__((ext_vector_type(4)));
typedef u32 u32x4 __attribute__((ext_vector_type(4)));

#define IN_DIM 512

__device__ __forceinline__ u16 bfr(float f) {
  __bf16 h = (__bf16)f;
  return __builtin_bit_cast(u16, h);
}
__device__ __forceinline__ u16 f2bf(float f) {
  u32 u = __builtin_bit_cast(u32, f);
  u += 0x7fffu + ((u >> 16) & 1u);
  return (u16)(u >> 16);
}
__device__ __forceinline__ u32 pk2(float a, float b) {
  return (u32)f2bf(a) | ((u32)f2bf(b) << 16);
}

// ---------------------------------------------------------------------------
// pack_b: B packed in MFMA-fragment order (L2->VGPR direct in the GEMM).
// Chunk(nbp, s, cb, ks) = 64 lanes x 16B; lane l holds
//   col = nbp*128 + cb*16 + (l&15), kexp = s*64 + ks*32 + (l>>4)*8 .. +7
// Per (col,dim) 16 slots: 0..12 coeffs, 13=W, 14=W, 15=0.
// ---------------------------------------------------------------------------
__global__ void pack_b(const float* __restrict__ coeffs,
                       const float* __restrict__ bw,
                       char* __restrict__ Bp) {
  __shared__ float stage[64][56];
  const int tid = threadIdx.x;
  const int q = tid & 3, g = tid >> 2;
  const int id = blockIdx.x * 64 + g;          // (col, s) pair
  const int col = id >> 7, s = id & 127;
  const float* cbase = coeffs + ((size_t)col * IN_DIM + s * 4) * 13;
#pragma unroll
  for (int j = 0; j < 3; ++j) {
    int ch = q + j * 4;
    float4 v = *(const float4*)(cbase + ch * 4);
    stage[g][ch * 4 + 0] = v.x; stage[g][ch * 4 + 1] = v.y;
    stage[g][ch * 4 + 2] = v.z; stage[g][ch * 4 + 3] = v.w;
  }
  if (q == 0) {
    float4 v = *(const float4*)(cbase + 48);
    stage[g][48] = v.x; stage[g][49] = v.y; stage[g][50] = v.z; stage[g][51] = v.w;
  }
  if (q == 1) {
    float4 v = *(const float4*)(bw + (size_t)col * IN_DIM + s * 4);
    stage[g][52] = v.x; stage[g][53] = v.y; stage[g][54] = v.z; stage[g][55] = v.w;
  }
  __syncthreads();
  const int nbp = col >> 7, cb = (col >> 4) & 7, cl = col & 15;
  char* base = Bp + (((size_t)(nbp * 128 + s) * 8 + cb) * 2) * 1024;
#pragma unroll
  for (int r = 0; r < 2; ++r) {
    int idx = q * 2 + r;
    int h = idx & 1;
    int dd = idx >> 1;              // dim-in-step 0..3
    int ks = dd >> 1;
    const float* sf = &stage[g][dd * 13];
    float w = stage[g][52 + dd];
    u16 hh[8];
#pragma unroll
    for (int c = 0; c < 8; ++c) {
      int slot = h * 8 + c;
      float v = slot < 13 ? sf[slot] : (slot < 15 ? w : 0.0f);
      hh[c] = bfr(v);
    }
    u32x4 o;
    o.x = (u32)hh[0] | ((u32)hh[1] << 16);
    o.y = (u32)hh[2] | ((u32)hh[3] << 16);
    o.z = (u32)hh[4] | ((u32)hh[5] << 16);
    o.w = (u32)hh[6] | ((u32)hh[7] << 16);
    int lanei = cl + 16 * (2 * (dd & 1) + h);
    *(u32x4*)(base + (size_t)ks * 1024 + lanei * 16) = o;
  }
}

// ---------------------------------------------------------------------------
// A expansion: one x -> 16 bf16 K-slots as two swizzled ds_write_b128.
// ---------------------------------------------------------------------------
__device__ __forceinline__ void expandA(float xv, char* rb, u32 swz, u32 k0) {
  float xc = fminf(fmaxf(xv, -0.9999f), 0.9999f);
  float tp = __fmaf_rn(xc, 2.5f, 3.0f);
  float fj = floorf(tp);
  int jl = (int)fj;  // 0..5
  float u = tp - fj;
  float u2 = u * u, u3 = u2 * u;
  float vv = 1.0f - u;
  float b0 = vv * vv * vv * (1.0f / 6.0f);
  float b3 = u3 * (1.0f / 6.0f);
  float b1 = __fmaf_rn(0.5f, u3, __fmaf_rn(u2, -1.0f, 2.0f / 3.0f));
  float b2 = 1.0f - b0 - b1 - b3;
  float e = __expf(-xv);
  float sg = __fdividef(xv, 1.0f + e);
  u16 sh = bfr(sg);
  float shf = __builtin_bit_cast(float, ((u32)sh) << 16);
  u16 sl = bfr(sg - shf);
  u32 pk01 = (u32)bfr(b0) | ((u32)bfr(b1) << 16);
  u32 pk23 = (u32)bfr(b2) | ((u32)bfr(b3) << 16);
  u64 v = (u64)pk01 | (((u64)pk23) << 32);
  int sstart = jl + 2;       // 2..7
  int qa = sstart >> 2;
  int shn = (sstart & 3) << 4;
  u64 lo = v << shn;
  u64 hi = shn ? (v >> (64 - shn)) : 0ull;
  u64 q0 = qa ? 0ull : lo;
  u64 q1 = qa ? lo : hi;
  u64 q2 = qa ? hi : 0ull;
  u64 q3 = (u64)(((u32)sh) << 16) | (((u64)(u32)sl) << 32);
  u32x4 c0, c1;
  c0.x = (u32)q0; c0.y = (u32)(q0 >> 32); c0.z = (u32)q1; c0.w = (u32)(q1 >> 32);
  c1.x = (u32)q2; c1.y = (u32)(q2 >> 32); c1.z = (u32)q3; c1.w = (u32)(q3 >> 32);
  *(u32x4*)(rb + ((k0 ^ swz) << 4)) = c0;
  *(u32x4*)(rb + (((k0 + 1u) ^ swz) << 4)) = c1;
}

// ---------------------------------------------------------------------------
// Main GEMM, wave-specialized, 4-STEP SYNC INTERVALS (barrier amortization):
// 32 lgkm-only barriers instead of 128. A flows through two 64KB interval
// buffers: expansion (waves 8-11) fills interval i+1 while compute
// (waves 0-7) consumes interval i's 4 steps back-to-back with rolling
// register double-buffers (af0/af1, bA/bB) and NO intra-interval syncs.
// x loads are issued a full interval (~3000cy) ahead of use.
// ---------------------------------------------------------------------------
#define MM(AF, BV)                                                             \
  {                                                                            \
    __builtin_amdgcn_s_setprio(1);                                             \
    _Pragma("unroll")                                                          \
    for (int fm = 0; fm < 4; ++fm)                                             \
      _Pragma("unroll")                                                        \
      for (int fn = 0; fn < 4; ++fn)                                           \
        acc[fm][fn] = __builtin_amdgcn_mfma_f32_16x16x32_bf16(                 \
            __builtin_bit_cast(bf16x8, AF[fm]),                                \
            __builtin_bit_cast(bf16x8, BV[fn]), acc[fm][fn], 0, 0, 0);         \
    __builtin_amdgcn_s_setprio(0);                                             \
  }

__launch_bounds__(768, 3)
__global__ void kan_gemm(const float* __restrict__ x,
                         const char* __restrict__ Bp,
                         float* __restrict__ out) {
  __shared__ __align__(16) char smem[131072];  // 2 x 64KB interval buffers

  const int tid = threadIdx.x;
  const int lane = tid & 63;
  const int wid = tid >> 6;
  const bool isC = (wid < 8);

  const int kt = wid >> 2;             // 0/1 (compute K-split team)
  const int wm = (wid >> 1) & 1, wn = wid & 1;
  const int lrow = lane & 15, lkg = lane >> 4;

  int s0 = blockIdx.x;
  int xcd = s0 & 7;
  int nb = xcd >> 1;                   // XCD pair owns one 2MB B panel in L2
  int mb = ((s0 >> 3) << 1) | (xcd & 1);  // 0..63

  // expand-wave decomposition: 256 threads; thread owns rows (erow, erow+64), dim ad
  const int te = tid & 255;
  const int erow = te >> 2;            // 0..63
  const int ad = te & 3;
  const u32 aswz = (u32)(erow & 7);
  const u32 ak0 = (u32)(ad * 2);
  const float* xpa = x + (size_t)(mb * 128 + erow) * IN_DIM + ad;
  const float* xpb = xpa + (size_t)64 * IN_DIM;

  const char* bptr = Bp + (((size_t)(nb * 128) * 8 + wn * 4) * 2 + kt) * 1024 + (size_t)lane * 16;

  f32x4 acc[4][4];
#pragma unroll
  for (int i = 0; i < 4; ++i)
#pragma unroll
    for (int j = 0; j < 4; ++j) acc[i][j] = (f32x4){0.f, 0.f, 0.f, 0.f};

  u32x4 bA[4], bB[4];
  char* ab0 = smem;            // interval buffer 0 (even intervals)
  char* ab1 = smem + 65536;    // interval buffer 1 (odd intervals)

  float xc[8];                 // x values for interval iv+1 (expansion waves)
#pragma unroll
  for (int j = 0; j < 8; ++j) xc[j] = 0.f;

  if (isC) {
#pragma unroll
    for (int fn = 0; fn < 4; ++fn)
      bA[fn] = *(const u32x4*)(bptr + fn * 2048);
  } else {
    // prologue: expand interval 0 into ab0; preload x for interval 1
    float xi[8];
#pragma unroll
    for (int k = 0; k < 4; ++k) { xi[2 * k] = xpa[4 * k]; xi[2 * k + 1] = xpb[4 * k]; }
#pragma unroll
    for (int k = 0; k < 4; ++k) {
      expandA(xi[2 * k],     ab0 + k * 16384 + erow * 128, aswz, ak0);
      expandA(xi[2 * k + 1], ab0 + k * 16384 + (erow + 64) * 128, aswz, ak0);
    }
#pragma unroll
    for (int k = 0; k < 4; ++k) { xc[2 * k] = xpa[16 + 4 * k]; xc[2 * k + 1] = xpb[16 + 4 * k]; }
  }
  __syncthreads();   // one-time full drain (interval 0 visible)

  const u32 asl = (((u32)(kt * 4) | (u32)lkg) ^ (u32)(lrow & 7)) << 4;

#pragma unroll 1
  for (int iv = 0; iv < 32; ++iv) {
    if (isC) {
      const char* rb = (iv & 1) ? ab1 : ab0;
      const char* arb = rb + (wm * 64 + lrow) * 128;
      const int S = iv * 4;
      u32x4 af0[4], af1[4];
      // interval-top: frags for step 0
#pragma unroll
      for (int fm = 0; fm < 4; ++fm)
        af0[fm] = *(const u32x4*)(arb + fm * 2048 + asl);
      // k=0: prefetch step1 frags + B(S+1); MFMA step0
#pragma unroll
      for (int fm = 0; fm < 4; ++fm)
        af1[fm] = *(const u32x4*)(arb + 16384 + fm * 2048 + asl);
#pragma unroll
      for (int fn = 0; fn < 4; ++fn)
        bB[fn] = *(const u32x4*)(bptr + (size_t)(S + 1) * 16384 + fn * 2048);
      MM(af0, bA)
      // k=1: prefetch step2 frags + B(S+2); MFMA step1
#pragma unroll
      for (int fm = 0; fm < 4; ++fm)
        af0[fm] = *(const u32x4*)(arb + 2 * 16384 + fm * 2048 + asl);
#pragma unroll
      for (int fn = 0; fn < 4; ++fn)
        bA[fn] = *(const u32x4*)(bptr + (size_t)(S + 2) * 16384 + fn * 2048);
      MM(af1, bB)
      // k=2: prefetch step3 frags + B(S+3); MFMA step2
#pragma unroll
      for (int fm = 0; fm < 4; ++fm)
        af1[fm] = *(const u32x4*)(arb + 3 * 16384 + fm * 2048 + asl);
#pragma unroll
      for (int fn = 0; fn < 4; ++fn)
        bB[fn] = *(const u32x4*)(bptr + (size_t)(S + 3) * 16384 + fn * 2048);
      MM(af0, bA)
      // k=3: prefetch B(next interval step0); MFMA step3
      {
        int sn = (S + 4 < 128) ? (S + 4) : 127;
#pragma unroll
        for (int fn = 0; fn < 4; ++fn)
          bA[fn] = *(const u32x4*)(bptr + (size_t)sn * 16384 + fn * 2048);
      }
      MM(af1, bB)
    } else {
      // expansion: fill interval iv+1's buffer from xc (loaded last interval)
      if (iv + 1 < 32) {
        char* wb = (iv & 1) ? ab0 : ab1;
#pragma unroll
        for (int k = 0; k < 4; ++k) {
          expandA(xc[2 * k],     wb + k * 16384 + erow * 128, aswz, ak0);
          expandA(xc[2 * k + 1], wb + k * 16384 + (erow + 64) * 128, aswz, ak0);
        }
      }
      // load x for interval iv+2 (a full interval of latency cover)
      {
        int v2 = (iv + 2 < 32) ? (iv + 2) : 31;
        float xn[8];
#pragma unroll
        for (int k = 0; k < 4; ++k) {
          xn[2 * k]     = xpa[v2 * 16 + 4 * k];
          xn[2 * k + 1] = xpb[v2 * 16 + 4 * k];
        }
#pragma unroll
        for (int j = 0; j < 8; ++j) xc[j] = xn[j];
      }
      asm volatile("s_waitcnt lgkmcnt(0)" ::: "memory");
    }
    __builtin_amdgcn_s_barrier();
  }

  __syncthreads();  // full drain before smem reuse

  // epilogue: deterministic kt-reduction via LDS (stride 132 floats), +x
  float* red = (float*)smem;
  if (isC && kt == 1) {
#pragma unroll
    for (int fm = 0; fm < 4; ++fm)
#pragma unroll
      for (int fn = 0; fn < 4; ++fn) {
        int rr = wm * 64 + fm * 16 + lkg * 4;
        int cc = wn * 64 + fn * 16 + lrow;
#pragma unroll
        for (int r = 0; r < 4; ++r)
          red[(size_t)(rr + r) * 132 + cc] = acc[fm][fn][r];
      }
  }
  __syncthreads();
  if (isC && kt == 0) {
#pragma unroll
    for (int fm = 0; fm < 4; ++fm)
#pragma unroll
      for (int fn = 0; fn < 4; ++fn) {
        int rr = wm * 64 + fm * 16 + lkg * 4;
        int cc = wn * 64 + fn * 16 + lrow;
        size_t gb = (size_t)(mb * 128 + rr) * IN_DIM + nb * 128 + cc;
#pragma unroll
        for (int r = 0; r < 4; ++r) {
          size_t off = gb + (size_t)r * IN_DIM;
          out[off] = acc[fm][fn][r] + red[(size_t)(rr + r) * 132 + cc] + x[off];
        }
      }
  }
}

// ---------------------------------------------------------------------------
// Fallback (round-1 kernel) if ws too small for B_packed (8MB)
// ---------------------------------------------------------------------------
__device__ __forceinline__ void st_b16(char* rb, u32 swz, u32 k0, int c, u16 v) {
  u32 uc = (u32)c;
  u32 byte = (((k0 + (uc >> 3)) ^ swz) << 4) | ((uc & 7u) << 1);
  *(u16*)(rb + byte) = v;
}

__device__ __forceinline__ void stage_a_fb(char* aT, int row, int d, float xv) {
  char* rb = aT + row * 128;
  u32 swz = (u32)(row & 7);
  float xc = fminf(fmaxf(xv, -0.9999f), 0.9999f);
  float tp = __fmaf_rn(xc, 2.5f, 3.0f);
  float fj = floorf(tp);
  int jl = (int)fj;
  float u = tp - fj;
  float u2 = u * u, u3 = u2 * u;
  float vv = 1.0f - u;
  float b0 = vv * vv * vv * (1.0f / 6.0f);
  float b3 = u3 * (1.0f / 6.0f);
  float b1 = __fmaf_rn(0.5f, u3, __fmaf_rn(u2, -1.0f, 2.0f / 3.0f));
  float b2 = 1.0f - b0 - b1 - b3;
  float e = __expf(-xv);
  float sg = __fdividef(xv, 1.0f + e);
  u16 sh = f2bf(sg);
  float shf = __builtin_bit_cast(float, ((u32)sh) << 16);
  u16 slo = f2bf(sg - shf);
  u32 k0 = (u32)d * 2u;
  u32x4 z = {0u, 0u, 0u, 0u};
  *(u32x4*)(rb + ((k0 ^ swz) << 4)) = z;
  u32x4 z2 = {0u, 0u, ((u32)sh) << 16, (u32)slo};
  *(u32x4*)(rb + (((k0 + 1u) ^ swz) << 4)) = z2;
  st_b16(rb, swz, k0, jl + 2, f2bf(b0));
  st_b16(rb, swz, k0, jl + 3, f2bf(b1));
  st_b16(rb, swz, k0, jl + 4, f2bf(b2));
  st_b16(rb, swz, k0, jl + 5, f2bf(b3));
}

__launch_bounds__(512, 2)
__global__ void kan_fused(const float* __restrict__ x,
                          const float* __restrict__ coeffs,
                          const float* __restrict__ bw,
                          float* __restrict__ out) {
  __shared__ __align__(16) char smem[65536];
  const int tid = threadIdx.x;
  const int lane = tid & 63;
  const int wid = tid >> 6;
  const int team = wid >> 2;
  const int wm = (wid >> 1) & 1;
  const int wn = wid & 1;
  const int m0 = wm * 64, n0 = wn * 64;
  const int lrow = lane & 15;
  const int lkg = lane >> 4;
  int s = blockIdx.x;
  int xcd = s & 7;
  int nb = xcd >> 1;
  int mb = (s >> 3) | ((xcd & 1) << 5);
  const int t = tid & 255;
  const int arow = t >> 1;
  const int h = t & 1;
  char* aT = smem + team * 16384;
  char* bT = smem + 32768 + team * 16384;
  const int dim0 = team * 256;
  const float* xptr = x + (size_t)(mb * 128 + arow) * IN_DIM + dim0 + 2 * h;
  const float* cptr = coeffs + ((size_t)((nb * 128 + arow) * IN_DIM) + dim0) * 13 + 26 * h;
  const float* wptr = bw + (size_t)(nb * 128 + arow) * IN_DIM + dim0 + 2 * h;
  f32x4 acc[4][4];
#pragma unroll
  for (int i = 0; i < 4; ++i)
#pragma unroll
    for (int j = 0; j < 4; ++j) acc[i][j] = (f32x4){0.f, 0.f, 0.f, 0.f};
  float2 xv, wv;
  float2 cv0, cv1, cv2, cv3, cv4, cv5, cv6, cv7, cv8, cv9, cv10, cv11, cv12;
#define PREFETCH(STP)                                                     \
  {                                                                       \
    const float* cp_ = cptr + (STP) * 52;                                 \
    xv = *(const float2*)(xptr + (STP) * 4);                              \
    wv = *(const float2*)(wptr + (STP) * 4);                              \
    cv0 = *(const float2*)(cp_ + 0);   cv1 = *(const float2*)(cp_ + 2);   \
    cv2 = *(const float2*)(cp_ + 4);   cv3 = *(const float2*)(cp_ + 6);   \
    cv4 = *(const float2*)(cp_ + 8);   cv5 = *(const float2*)(cp_ + 10);  \
    cv6 = *(const float2*)(cp_ + 12);  cv7 = *(const float2*)(cp_ + 14);  \
    cv8 = *(const float2*)(cp_ + 16);  cv9 = *(const float2*)(cp_ + 18);  \
    cv10 = *(const float2*)(cp_ + 20); cv11 = *(const float2*)(cp_ + 22); \
    cv12 = *(const float2*)(cp_ + 24);                                    \
  }
  PREFETCH(0)
  for (int st = 0; st < 64; ++st) {
    stage_a_fb(aT, arow, 2 * h + 0, xv.x);
    stage_a_fb(aT, arow, 2 * h + 1, xv.y);
    {
      char* rb = bT + arow * 128;
      u32 swz = (u32)(arow & 7);
      u32 k0 = (u32)(2 * h) * 2u;
      u32x4 lo, hi;
      lo.x = pk2(cv0.x, cv0.y); lo.y = pk2(cv1.x, cv1.y);
      lo.z = pk2(cv2.x, cv2.y); lo.w = pk2(cv3.x, cv3.y);
      hi.x = pk2(cv4.x, cv4.y); hi.y = pk2(cv5.x, cv5.y);
      {
        u16 wb = f2bf(wv.x);
        hi.z = (u32)f2bf(cv6.x) | ((u32)wb << 16);
        hi.w = (u32)wb;
      }
      *(u32x4*)(rb + ((k0 ^ swz) << 4)) = lo;
      *(u32x4*)(rb + (((k0 + 1u) ^ swz) << 4)) = hi;
      lo.x = pk2(cv6.y, cv7.x);  lo.y = pk2(cv7.y, cv8.x);
      lo.z = pk2(cv8.y, cv9.x);  lo.w = pk2(cv9.y, cv10.x);
      hi.x = pk2(cv10.y, cv11.x); hi.y = pk2(cv11.y, cv12.x);
      {
        u16 wb = f2bf(wv.y);
        hi.z = (u32)f2bf(cv12.y) | ((u32)wb << 16);
        hi.w = (u32)wb;
      }
      *(u32x4*)(rb + (((k0 + 2u) ^ swz) << 4)) = lo;
      *(u32x4*)(rb + (((k0 + 3u) ^ swz) << 4)) = hi;
    }
    __syncthreads();
    if (st != 63) { PREFETCH(st + 1) }
    {
      const char* arb = aT + (m0 + lrow) * 128;
      const char* brb = bT + (n0 + lrow) * 128;
      u32 rsw = (u32)(lrow & 7);
#pragma unroll
      for (int ks = 0; ks < 2; ++ks) {
        u32 sl2 = (((u32)(ks * 4) | (u32)lkg) ^ rsw) << 4;
        bf16x8 af[4], bfr2[4];
#pragma unroll
        for (int fm = 0; fm < 4; ++fm)
          af[fm] = __builtin_bit_cast(bf16x8, *(const u32x4*)(arb + fm * 2048 + sl2));
#pragma unroll
        for (int fn = 0; fn < 4; ++fn)
          bfr2[fn] = __builtin_bit_cast(bf16x8, *(const u32x4*)(brb + fn * 2048 + sl2));
#pragma unroll
        for (int fm = 0; fm < 4; ++fm)
#pragma unroll
          for (int fn = 0; fn < 4; ++fn)
            acc[fm][fn] = __builtin_amdgcn_mfma_f32_16x16x32_bf16(
                af[fm], bfr2[fn], acc[fm][fn], 0, 0, 0);
      }
    }
    __syncthreads();
  }
  float* red = (float*)smem;
  if (team == 1) {
#pragma unroll
    for (int fm = 0; fm < 4; ++fm)
#pragma unroll
      for (int fn = 0; fn < 4; ++fn) {
        int rr = m0 + fm * 16 + lkg * 4;
        int cc = n0 + fn * 16 + lrow;
#pragma unroll
        for (int r = 0; r < 4; ++r) red[(rr + r) * 128 + cc] = acc[fm][fn][r];
      }
  }
  __syncthreads();
  if (team == 0) {
#pragma unroll
    for (int fm = 0; fm < 4; ++fm)
#pragma unroll
      for (int fn = 0; fn < 4; ++fn) {
        int rr = m0 + fm * 16 + lkg * 4;
        int ccol = n0 + fn * 16 + lrow;
        int grow = mb * 128 + rr;
        int gcol = nb * 128 + ccol;
#pragma unroll
        for (int r = 0; r < 4; ++r) {
          float v = acc[fm][fn][r] + red[(rr + r) * 128 + ccol] +
                    x[(size_t)(grow + r) * IN_DIM + gcol];
          out[(size_t)(grow + r) * IN_DIM + gcol] = v;
        }
      }
  }
}

extern "C" void kernel_launch(void* const* d_in, const int* in_sizes, int n_in,
                              void* d_out, int out_size, void* d_ws, size_t ws_size,
                              hipStream_t stream) {
  const float* x = (const float*)d_in[0];
  const float* coeffs = (const float*)d_in[1];
  const float* bw = (const float*)d_in[2];
  float* out = (float*)d_out;
  if (ws_size >= (size_t)512 * 16384) {  // 8 MB for B_packed
    char* Bp = (char*)d_ws;
    hipLaunchKernelGGL(pack_b, dim3(1024), dim3(256), 0, stream, coeffs, bw, Bp);
    hipLaunchKernelGGL(kan_gemm, dim3(256), dim3(768), 0, stream, x, Bp, out);
  } else {
    hipLaunchKernelGGL(kan_fused, dim3(256), dim3(512), 0, stream, x, coeffs, bw, out);
  }
}